// Round 1
// baseline (618.640 us; speedup 1.0000x reference)
//
#include <hip/hip_runtime.h>

#define NB 4
#define NS 512
#define NC 128
#define NV 128

typedef _Float16 half8 __attribute__((ext_vector_type(8)));
typedef float f32x4 __attribute__((ext_vector_type(4)));

__device__ __forceinline__ float fast_tanh(float x) {
  float e = __expf(2.0f * x);
  return 1.0f - __fdividef(2.0f, e + 1.0f);
}

// ---------------- prep kernel ----------------
// H[b,j,v] = ctx[b,j]·(W1+Wd)[v] + b1[v]
// G[b,i,v] = ctx[b,i]·(W2-Wd)[v] + b2[v]+bd[v]+bm[v]
// ctx_h = fp16(ctx)
// grid: NB*NS/8 blocks, 128 threads
__global__ __launch_bounds__(128) void prep_kernel(
    const float* __restrict__ ctx,
    const float* __restrict__ W1, const float* __restrict__ b1,
    const float* __restrict__ W2, const float* __restrict__ b2,
    const float* __restrict__ bm,
    const float* __restrict__ Wd, const float* __restrict__ bd,
    _Float16* __restrict__ ctx_h,
    float* __restrict__ H, float* __restrict__ G)
{
  __shared__ float xr[8][NC];
  const int row0 = blockIdx.x * 8;
  const int t = threadIdx.x;
  #pragma unroll
  for (int rr = 0; rr < 8; ++rr) {
    float x = ctx[(size_t)(row0 + rr) * NC + t];
    xr[rr][t] = x;
    ctx_h[(size_t)(row0 + rr) * NC + t] = (_Float16)x;
  }
  __syncthreads();
  const int v = t;
  float accH[8], accG[8];
  const float bH = b1[v];
  const float bG = b2[v] + bd[v] + bm[v];
  #pragma unroll
  for (int rr = 0; rr < 8; ++rr) { accH[rr] = bH; accG[rr] = bG; }
  for (int c4 = 0; c4 < NC; c4 += 4) {
    f32x4 w1 = *(const f32x4*)(W1 + v * NC + c4);
    f32x4 w2 = *(const f32x4*)(W2 + v * NC + c4);
    f32x4 wd = *(const f32x4*)(Wd + v * NC + c4);
    #pragma unroll
    for (int u = 0; u < 4; ++u) {
      const float wH = w1[u] + wd[u];
      const float wG = w2[u] - wd[u];
      const int c = c4 + u;
      #pragma unroll
      for (int rr = 0; rr < 8; ++rr) {
        accH[rr] = fmaf(xr[rr][c], wH, accH[rr]);
        accG[rr] = fmaf(xr[rr][c], wG, accG[rr]);
      }
    }
  }
  #pragma unroll
  for (int rr = 0; rr < 8; ++rr) {
    H[(size_t)(row0 + rr) * NV + v] = accH[rr];
    G[(size_t)(row0 + rr) * NV + v] = accG[rr];
  }
}

// ---------------- main kernel ----------------
// One block per (b,i). out[b,i,j,v] = tanh(H[b,j,v] + G[b,i,v] + ctx_j · (Wm ⊙ ctx_i))
// 256 threads = 4 waves; wave w handles j-strips j0 = tt*64 + w*16.
__global__ __launch_bounds__(256, 2) void main_kernel(
    const float* __restrict__ ctx,
    const float* __restrict__ Wm,
    const _Float16* __restrict__ ctx_h,
    const float* __restrict__ H,
    const float* __restrict__ G,
    float* __restrict__ out)
{
  const int bx = blockIdx.x;
  const int b = bx >> 9;          // NS = 512
  const int i = bx & (NS - 1);
  const int tid = threadIdx.x;
  const int w = tid >> 6;
  const int l = tid & 63;
  const int r = l & 15;           // row-in-16 / v-in-16 lane index
  const int q = l >> 4;           // quarter-wave → k-block / output-row group

  __shared__ _Float16 Bm[NV][NC + 8];   // +8 halfs (16B) pad: breaks 256B-stride bank conflict

  // Build Bm[v][c] = fp16(Wm[v][c] * ctx[b][i][c]) cooperatively (fp32 multiply, one rounding)
  const float* xi = ctx + (size_t)(b * NS + i) * NC;
  for (int idx = tid; idx < NV * (NC / 8); idx += 256) {
    const int v = idx >> 4;
    const int c0 = (idx & 15) * 8;
    f32x4 wa = *(const f32x4*)(Wm + v * NC + c0);
    f32x4 wb = *(const f32x4*)(Wm + v * NC + c0 + 4);
    f32x4 xa = *(const f32x4*)(xi + c0);
    f32x4 xb = *(const f32x4*)(xi + c0 + 4);
    half8 h;
    h[0] = (_Float16)(wa[0] * xa[0]);
    h[1] = (_Float16)(wa[1] * xa[1]);
    h[2] = (_Float16)(wa[2] * xa[2]);
    h[3] = (_Float16)(wa[3] * xa[3]);
    h[4] = (_Float16)(wb[0] * xb[0]);
    h[5] = (_Float16)(wb[1] * xb[1]);
    h[6] = (_Float16)(wb[2] * xb[2]);
    h[7] = (_Float16)(wb[3] * xb[3]);
    *(half8*)&Bm[v][c0] = h;
  }
  __syncthreads();

  // Hoist all B fragments into registers: 8 n-tiles × 4 k-steps × 4 VGPR = 128 VGPRs.
  // B-frag lane layout: col = l&15 (v), k = (l>>4)*8 + e  → contiguous 8 halfs of row v.
  half8 Bf[8][4];
  #pragma unroll
  for (int n = 0; n < 8; ++n) {
    #pragma unroll
    for (int ks = 0; ks < 4; ++ks) {
      Bf[n][ks] = *(const half8*)&Bm[n * 16 + r][ks * 32 + q * 8];
    }
  }

  // G values for this lane (v = 16n + r), constant over j
  float Gv[8];
  const float* gp = G + (size_t)(b * NS + i) * NV;
  #pragma unroll
  for (int n = 0; n < 8; ++n) Gv[n] = gp[n * 16 + r];

  const _Float16* ah_base = ctx_h + (size_t)(b * NS) * NC;
  const float* h_base = H + (size_t)(b * NS) * NV;
  float* out_base = out + ((size_t)(b * NS + i) * NS) * NV;

  for (int tt = 0; tt < 8; ++tt) {
    const int j0 = tt * 64 + w * 16;

    // A fragments: row = j0 + (l&15), k = (l>>4)*8 + e → 16B load from fp16 ctx (L2-resident)
    half8 A[4];
    const _Float16* ap = ah_base + (size_t)(j0 + r) * NC + q * 8;
    #pragma unroll
    for (int ks = 0; ks < 4; ++ks) A[ks] = *(const half8*)(ap + ks * 32);

    f32x4 acc[8];
    #pragma unroll
    for (int n = 0; n < 8; ++n) acc[n] = (f32x4){0.f, 0.f, 0.f, 0.f};

    #pragma unroll
    for (int ks = 0; ks < 4; ++ks) {
      #pragma unroll
      for (int n = 0; n < 8; ++n) {
        acc[n] = __builtin_amdgcn_mfma_f32_16x16x32_f16(A[ks], Bf[n][ks], acc[n], 0, 0, 0);
      }
    }

    // Epilogue: C/D layout col = l&15 (v), row = (l>>4)*4 + rr (j offset)
    const float* hp = h_base + (size_t)j0 * NV;
    float* op = out_base + (size_t)j0 * NV;
    #pragma unroll
    for (int n = 0; n < 8; ++n) {
      const int v = n * 16 + r;
      #pragma unroll
      for (int rr = 0; rr < 4; ++rr) {
        const int j = q * 4 + rr;
        const float pre = acc[n][rr] + hp[j * NV + v] + Gv[n];
        op[j * NV + v] = fast_tanh(pre);
      }
    }
  }
}

extern "C" void kernel_launch(void* const* d_in, const int* in_sizes, int n_in,
                              void* d_out, int out_size, void* d_ws, size_t ws_size,
                              hipStream_t stream) {
  const float* ctx = (const float*)d_in[0];
  const float* W1  = (const float*)d_in[1];
  const float* b1  = (const float*)d_in[2];
  const float* W2  = (const float*)d_in[3];
  const float* b2  = (const float*)d_in[4];
  const float* Wm  = (const float*)d_in[5];
  const float* bm  = (const float*)d_in[6];
  const float* Wd  = (const float*)d_in[7];
  const float* bd  = (const float*)d_in[8];
  float* out = (float*)d_out;

  char* ws = (char*)d_ws;
  _Float16* ctx_h = (_Float16*)ws;                               // 512 KB
  float* H = (float*)(ws + (size_t)NB * NS * NC * sizeof(_Float16));
  float* G = H + (size_t)NB * NS * NV;                           // 1 MB each

  prep_kernel<<<NB * NS / 8, 128, 0, stream>>>(ctx, W1, b1, W2, b2, bm, Wd, bd, ctx_h, H, G);
  main_kernel<<<NB * NS, 256, 0, stream>>>(ctx, Wm, ctx_h, H, G, out);
}

// Round 3
// 607.532 us; speedup vs baseline: 1.0183x; 1.0183x over previous
//
#include <hip/hip_runtime.h>

#define NB 4
#define NS 512
#define NC 128
#define NV 128

typedef _Float16 half8 __attribute__((ext_vector_type(8)));
typedef float f32x4 __attribute__((ext_vector_type(4)));

__device__ __forceinline__ float fast_tanh(float x) {
  float e = __expf(2.0f * x);
  return 1.0f - __fdividef(2.0f, e + 1.0f);
}

// ---------------- prep kernel ----------------
// Gp[b,i,v]  = ctx[b,i]·(W2-Wd)[v] + (b1+b2+bm+bd)[v]   (all i-only + const terms)
// WHd[v,c]   = W1[v,c] + Wd[v,c]                        (j-side weight fold)
// ctx_h      = fp16(ctx)
// grid: NB*NS/8 = 256 blocks, 128 threads
__global__ __launch_bounds__(128) void prep_kernel(
    const float* __restrict__ ctx,
    const float* __restrict__ W1, const float* __restrict__ b1,
    const float* __restrict__ W2, const float* __restrict__ b2,
    const float* __restrict__ bm,
    const float* __restrict__ Wd, const float* __restrict__ bd,
    _Float16* __restrict__ ctx_h,
    float* __restrict__ Gp,
    float* __restrict__ WHd)
{
  __shared__ float xr[8][NC];
  const int row0 = blockIdx.x * 8;
  const int t = threadIdx.x;

  // WHd = W1 + Wd, sliced across the 256 blocks (64 entries each)
  {
    const int base = blockIdx.x * 64;
    if (t < 64) WHd[base + t] = W1[base + t] + Wd[base + t];
  }

  #pragma unroll
  for (int rr = 0; rr < 8; ++rr) {
    float x = ctx[(size_t)(row0 + rr) * NC + t];
    xr[rr][t] = x;
    ctx_h[(size_t)(row0 + rr) * NC + t] = (_Float16)x;
  }
  __syncthreads();

  const int v = t;
  float acc[8];
  const float bG = b1[v] + b2[v] + bm[v] + bd[v];
  #pragma unroll
  for (int rr = 0; rr < 8; ++rr) acc[rr] = bG;

  for (int c4 = 0; c4 < NC; c4 += 4) {
    f32x4 w2 = *(const f32x4*)(W2 + v * NC + c4);
    f32x4 wd = *(const f32x4*)(Wd + v * NC + c4);
    #pragma unroll
    for (int u = 0; u < 4; ++u) {
      const float wG = w2[u] - wd[u];
      const int c = c4 + u;
      #pragma unroll
      for (int rr = 0; rr < 8; ++rr) acc[rr] = fmaf(xr[rr][c], wG, acc[rr]);
    }
  }
  #pragma unroll
  for (int rr = 0; rr < 8; ++rr) Gp[(size_t)(row0 + rr) * NV + v] = acc[rr];
}

// ---------------- main kernel ----------------
// One block per (b,i).
// out[b,i,j,v] = tanh( ctx_j · Bm'[v] + Gp[b,i,v] ),  Bm'[v,c] = Wm[v,c]*ctx_i[c] + WHd[v,c]
// MFMA with Bm' as the A-operand (M = v), ctx_j as the B-operand (N = j):
// D lane layout: col = l&15 -> j-offset, row = (l>>4)*4+reg -> v-offset
// => each lane holds 4 consecutive v => float4 stores.
__global__ __launch_bounds__(256, 2) void main_kernel(
    const float* __restrict__ ctx,
    const float* __restrict__ Wm,
    const float* __restrict__ WHd,
    const _Float16* __restrict__ ctx_h,
    const float* __restrict__ Gp,
    float* __restrict__ out)
{
  const int bx = blockIdx.x;
  const int b = bx >> 9;          // NS = 512
  const int i = bx & (NS - 1);
  const int tid = threadIdx.x;
  const int w = tid >> 6;
  const int l = tid & 63;
  const int r = l & 15;
  const int q = l >> 4;

  __shared__ _Float16 Bm[NV][NC + 8];   // +16B pad per row

  // Bm'[v][c] = fp16(Wm[v][c]*ctx_i[c] + WHd[v][c])
  const float* xi = ctx + (size_t)(b * NS + i) * NC;
  for (int idx = tid; idx < NV * (NC / 8); idx += 256) {
    const int v = idx >> 4;
    const int c0 = (idx & 15) * 8;
    f32x4 wa = *(const f32x4*)(Wm + v * NC + c0);
    f32x4 wb = *(const f32x4*)(Wm + v * NC + c0 + 4);
    f32x4 ha = *(const f32x4*)(WHd + v * NC + c0);
    f32x4 hb = *(const f32x4*)(WHd + v * NC + c0 + 4);
    f32x4 xa = *(const f32x4*)(xi + c0);
    f32x4 xb = *(const f32x4*)(xi + c0 + 4);
    half8 h;
    h[0] = (_Float16)fmaf(wa[0], xa[0], ha[0]);
    h[1] = (_Float16)fmaf(wa[1], xa[1], ha[1]);
    h[2] = (_Float16)fmaf(wa[2], xa[2], ha[2]);
    h[3] = (_Float16)fmaf(wa[3], xa[3], ha[3]);
    h[4] = (_Float16)fmaf(wb[0], xb[0], hb[0]);
    h[5] = (_Float16)fmaf(wb[1], xb[1], hb[1]);
    h[6] = (_Float16)fmaf(wb[2], xb[2], hb[2]);
    h[7] = (_Float16)fmaf(wb[3], xb[3], hb[7 - 7 + 3]);
    *(half8*)&Bm[v][c0] = h;
  }
  __syncthreads();

  // Hoist all B' fragments (A-operand): row = l&15 -> v, k = (l>>4)*8+e
  half8 Bf[8][4];
  #pragma unroll
  for (int n = 0; n < 8; ++n) {
    #pragma unroll
    for (int ks = 0; ks < 4; ++ks) {
      Bf[n][ks] = *(const half8*)&Bm[n * 16 + r][ks * 32 + q * 8];
    }
  }

  // Per-lane accumulator init vector: Gp[b,i, n*16 + q*4 + reg] (float4)
  f32x4 Gv[8];
  const float* gp = Gp + (size_t)(b * NS + i) * NV;
  #pragma unroll
  for (int n = 0; n < 8; ++n) Gv[n] = *(const f32x4*)(gp + n * 16 + q * 4);

  const _Float16* ah_base = ctx_h + (size_t)(b * NS) * NC;
  float* out_base = out + ((size_t)(b * NS + i) * NS) * NV;

  for (int tt = 0; tt < 8; ++tt) {
    const int j0 = tt * 64 + w * 16;

    // ctx_j fragments (B-operand): col = l&15 -> j, k = (l>>4)*8+e
    half8 A[4];
    const _Float16* ap = ah_base + (size_t)(j0 + r) * NC + q * 8;
    #pragma unroll
    for (int ks = 0; ks < 4; ++ks) A[ks] = *(const half8*)(ap + ks * 32);

    f32x4 acc[8];
    #pragma unroll
    for (int n = 0; n < 8; ++n) acc[n] = Gv[n];   // fold i-side affine into C-init

    #pragma unroll
    for (int ks = 0; ks < 4; ++ks) {
      #pragma unroll
      for (int n = 0; n < 8; ++n) {
        acc[n] = __builtin_amdgcn_mfma_f32_16x16x32_f16(Bf[n][ks], A[ks], acc[n], 0, 0, 0);
      }
    }

    // Epilogue: lane writes out[b,i, j0+r, n*16 + q*4 .. +3] as float4
    float* op = out_base + (size_t)(j0 + r) * NV + q * 4;
    #pragma unroll
    for (int n = 0; n < 8; ++n) {
      f32x4 o;
      #pragma unroll
      for (int rr = 0; rr < 4; ++rr) o[rr] = fast_tanh(acc[n][rr]);
      *(f32x4*)(op + n * 16) = o;
    }
  }
}

extern "C" void kernel_launch(void* const* d_in, const int* in_sizes, int n_in,
                              void* d_out, int out_size, void* d_ws, size_t ws_size,
                              hipStream_t stream) {
  const float* ctx = (const float*)d_in[0];
  const float* W1  = (const float*)d_in[1];
  const float* b1  = (const float*)d_in[2];
  const float* W2  = (const float*)d_in[3];
  const float* b2  = (const float*)d_in[4];
  const float* Wm  = (const float*)d_in[5];
  const float* bm  = (const float*)d_in[6];
  const float* Wd  = (const float*)d_in[7];
  const float* bd  = (const float*)d_in[8];
  float* out = (float*)d_out;

  char* ws = (char*)d_ws;
  _Float16* ctx_h = (_Float16*)ws;                                   // 512 KB
  float* Gp  = (float*)(ws + (size_t)NB * NS * NC * sizeof(_Float16)); // 1 MB
  float* WHd = Gp + (size_t)NB * NS * NV;                            // 64 KB

  prep_kernel<<<NB * NS / 8, 128, 0, stream>>>(ctx, W1, b1, W2, b2, bm, Wd, bd, ctx_h, Gp, WHd);
  main_kernel<<<NB * NS, 256, 0, stream>>>(ctx, Wm, WHd, ctx_h, Gp, out);
}